// Round 5
// baseline (331.169 us; speedup 1.0000x reference)
//
#include <hip/hip_runtime.h>

// Additive attention, factored:
//   scores[b,q,k] = sum_h w_h * tanh(qp+kp) ;  tanh(x) = 1 - 2/(1+e^{2x})
//   e^{2(qp+kp)} = Eq*Ek  (Eq=e^{2qp}, Ek=e^{2kp} precomputed)
// With a = sum_h w_h/(1+Eq*Ek): score = const - 2a  ->  softmax = min-form
// over a: p = exp2((min_a - a)*2*log2e). Inner loop = fma+rcp+fma per (q,k,h).
//
// K0: repack W -> W4T[g][h] float4 (g = d/4).
// K1: proj+exp, d-chunked LDS staging (X 4KB + W 32KB SoA, conflict-free).
// K2: fused scores + masked softmax + P@V per (b, 2q).
//     Score loop: register double-buffered ek prefetch (8 deep), per-h
//     constants from one broadcast ds_read_b128 (eqpack), zero s_loads in loop.

#define Bb 8
#define Qn 256
#define Kk 1024
#define Dd 256
#define Hh 128
#define DVv 128

__device__ __forceinline__ float fexp2(float x) { return __builtin_amdgcn_exp2f(x); }
__device__ __forceinline__ float frcp(float x)  { return __builtin_amdgcn_rcpf(x); }

// ---------------------------------------------------------------------------
// K0: W [H][D] -> W4T [D/4][H] float4. 64 blocks x 256 threads.
// ---------------------------------------------------------------------------
__global__ __launch_bounds__(256)
void repack_w(const float* __restrict__ Wq, const float* __restrict__ Wk,
              float4* __restrict__ Wq4T, float4* __restrict__ Wk4T)
{
    const int blk = blockIdx.x;
    const float* src = (blk < 32) ? Wq : Wk;
    float4*      dst = (blk < 32) ? Wq4T : Wk4T;
    const int idx = (blk & 31) * 256 + threadIdx.x;   // 8192 float4 per matrix
    const int g = idx >> 7;
    const int h = idx & 127;
    dst[idx] = *(const float4*)(src + (size_t)h * Dd + g * 4);
}

// ---------------------------------------------------------------------------
// K1: EqT[b][h][r] = exp2(2*log2e * X[r]·W[h]).
// 640 blocks x 256 threads; block = 16 rows x 128 h; thread = 4 rows x 2 h
// (h = hgrp, hgrp+64 -> consecutive-lane LDS reads, 2-way = free).
// ---------------------------------------------------------------------------
__global__ __launch_bounds__(256)
void proj_exp_kernel(const float* __restrict__ queries,
                     const float* __restrict__ keys,
                     const float4* __restrict__ Wq4T,
                     const float4* __restrict__ Wk4T,
                     float* __restrict__ EqT,
                     float* __restrict__ EkT)
{
    __shared__ float Xs[16 * 64];        // 4 KB   [row][d-in-chunk]
    __shared__ float Ws[4][16 * 128];    // 32 KB  [c][g-in-chunk*128 + h]

    const int blk = blockIdx.x;          // 0..127 queries, 128..639 keys
    const float* X; const float4* W4; float* outT; int RB; int i0;
    if (blk < 128) { X = queries; W4 = Wq4T; outT = EqT; RB = Qn; i0 = blk * 16; }
    else           { X = keys;    W4 = Wk4T; outT = EkT; RB = Kk; i0 = (blk - 128) * 16; }

    const int tid  = threadIdx.x;
    const int hgrp = tid & 63;                                   // lane
    const int rgrp = __builtin_amdgcn_readfirstlane(tid >> 6);   // wave = row-group

    float acc[4][2];
#pragma unroll
    for (int i = 0; i < 4; ++i) { acc[i][0] = 0.f; acc[i][1] = 0.f; }

    for (int c0 = 0; c0 < Dd; c0 += 64) {
        const int g0 = c0 >> 2;          // 16 float4-groups per chunk
        __syncthreads();
        {   // stage X tile: 16 rows x 64 d
            const int row = tid >> 4, c4 = (tid & 15) * 4;
            *(float4*)(Xs + row * 64 + c4) =
                *(const float4*)(X + (size_t)(i0 + row) * Dd + c0 + c4);
        }
#pragma unroll
        for (int s = 0; s < 8; ++s) {    // stage W tile: 16 g x 128 h, SoA
            const int idx = tid + 256 * s;
            const int g = idx >> 7, h = idx & 127;
            const float4 w = W4[(size_t)(g0 + g) * Hh + h];
            Ws[0][g * 128 + h] = w.x;
            Ws[1][g * 128 + h] = w.y;
            Ws[2][g * 128 + h] = w.z;
            Ws[3][g * 128 + h] = w.w;
        }
        __syncthreads();

#pragma unroll 4
        for (int g = 0; g < 16; ++g) {
            float4 x[4];
#pragma unroll
            for (int i = 0; i < 4; ++i)  // wave-uniform -> broadcast
                x[i] = *(const float4*)(Xs + (rgrp * 4 + i) * 64 + g * 4);
#pragma unroll
            for (int s = 0; s < 2; ++s) {
                const int h = hgrp + 64 * s;   // consecutive lanes -> free
                const float wx = Ws[0][g * 128 + h];
                const float wy = Ws[1][g * 128 + h];
                const float wz = Ws[2][g * 128 + h];
                const float ww = Ws[3][g * 128 + h];
#pragma unroll
                for (int i = 0; i < 4; ++i) {
                    acc[i][s] = fmaf(x[i].x, wx, acc[i][s]);
                    acc[i][s] = fmaf(x[i].y, wy, acc[i][s]);
                    acc[i][s] = fmaf(x[i].z, wz, acc[i][s]);
                    acc[i][s] = fmaf(x[i].w, ww, acc[i][s]);
                }
            }
        }
    }

    const int b    = i0 / RB;            // 16 | RB, never straddles b
    const int rloc = (i0 % RB) + rgrp * 4;
#pragma unroll
    for (int s = 0; s < 2; ++s) {
        float4 o;
        o.x = fexp2(acc[0][s] * 2.885390082f);   // e^{2x} = 2^{2x*log2e}
        o.y = fexp2(acc[1][s] * 2.885390082f);
        o.z = fexp2(acc[2][s] * 2.885390082f);
        o.w = fexp2(acc[3][s] * 2.885390082f);
        *(float4*)(outT + (size_t)b * Hh * RB + (size_t)(hgrp + 64 * s) * RB + rloc) = o;
    }
}

// ---------------------------------------------------------------------------
// K2: fused scores + masked softmax + P@V. 1024 blocks (qt<<3 | b) x 256 thr.
// ---------------------------------------------------------------------------
__global__ __launch_bounds__(256, 4)
void attn_kernel(const float* __restrict__ EqT,
                 const float* __restrict__ EkT,
                 const float* __restrict__ wv,
                 const float* __restrict__ values,
                 const int* __restrict__ valid_lens,
                 float* __restrict__ out)
{
    __shared__ float4 eqpk[Hh];          // 2 KB: (eq_q0, eq_q1, wv, 0) per h
    __shared__ float  s_a[2][Kk];        // 8 KB: a-scores then weights, stride-1
    __shared__ float4 s_part[3][2][32];  // 3 KB: PV partials
    __shared__ float  s_inv[2];

    const int blk  = blockIdx.x;
    const int b    = blk & 7;            // fastest-varying for load balance
    const int q0   = (blk >> 3) * 2;
    const int tid  = threadIdx.x;
    const int lane = tid & 63;
    const int wave = __builtin_amdgcn_readfirstlane(tid >> 6);
    const int len  = valid_lens[b];

    // ---- stage per-h constants (one-time, uncoalesced but tiny)
    if (tid < Hh) {
        const float2 eq = *(const float2*)(EqT + (size_t)b * Hh * Qn + (size_t)tid * Qn + q0);
        eqpk[tid] = make_float4(eq.x, eq.y, wv[tid], 0.f);
    }
    __syncthreads();

    const float* ekbase = EkT + (size_t)b * Hh * Kk;

    // ---- phase 1: a[q][k] = sum_h wv[h]/(1+Eq*Ek), ek double-buffer prefetch
    for (int k0 = 0; k0 < len; k0 += 256) {
        const int k = k0 + tid;
        if (k < len) {
            const float* ekp = ekbase + k;
            float a0 = 0.f, a1 = 0.f;
            float ekb[2][8];
#pragma unroll
            for (int i = 0; i < 8; ++i) ekb[0][i] = ekp[(size_t)i * Kk];
#pragma unroll
            for (int hc = 0; hc < Hh; hc += 8) {
                const int cur = (hc >> 3) & 1;
                if (hc + 8 < Hh) {
#pragma unroll
                    for (int i = 0; i < 8; ++i)
                        ekb[cur ^ 1][i] = ekp[(size_t)(hc + 8 + i) * Kk];
                }
#pragma unroll
                for (int i = 0; i < 8; ++i) {
                    const float4 c = eqpk[hc + i];          // broadcast b128
                    a0 = fmaf(c.z, frcp(fmaf(c.x, ekb[cur][i], 1.0f)), a0);
                    a1 = fmaf(c.z, frcp(fmaf(c.y, ekb[cur][i], 1.0f)), a1);
                }
            }
            s_a[0][k] = a0;              // stride-1, conflict-free
            s_a[1][k] = a1;
        }
    }
    __syncthreads();

    // ---- phase 2: min-form softmax; waves 0,1 own q = wave
    if (wave < 2) {
        const int q = wave;
        float mn = 3.0e38f;
        for (int i = lane; i < len; i += 64) mn = fminf(mn, s_a[q][i]);
#pragma unroll
        for (int off = 32; off > 0; off >>= 1) mn = fminf(mn, __shfl_xor(mn, off));
        float sum = 0.f;
        for (int i = lane; i < len; i += 64) {
            const float p = fexp2((mn - s_a[q][i]) * 2.885390082f);
            s_a[q][i] = p;
            sum += p;
        }
#pragma unroll
        for (int off = 32; off > 0; off >>= 1) sum += __shfl_xor(sum, off);
        if (lane == 0) s_inv[q] = frcp(sum);
    }
    __syncthreads();

    // ---- phase 3: P@V. 8 k-slices x (32 lanes x float4 = 128 v)
    {
        const int slice = tid >> 5;
        const int l32   = tid & 31;
        const int v4    = l32 << 2;
        const float* vp = values + (size_t)b * Kk * DVv + v4;
        float a[2][4];
#pragma unroll
        for (int q = 0; q < 2; ++q) { a[q][0]=0.f; a[q][1]=0.f; a[q][2]=0.f; a[q][3]=0.f; }
        for (int k = slice; k < len; k += 8) {
            const float4 val = *(const float4*)(vp + (size_t)k * DVv);
            const float w0 = s_a[0][k];  // half-wave same k -> broadcast
            const float w1 = s_a[1][k];
            a[0][0] = fmaf(w0, val.x, a[0][0]);
            a[0][1] = fmaf(w0, val.y, a[0][1]);
            a[0][2] = fmaf(w0, val.z, a[0][2]);
            a[0][3] = fmaf(w0, val.w, a[0][3]);
            a[1][0] = fmaf(w1, val.x, a[1][0]);
            a[1][1] = fmaf(w1, val.y, a[1][1]);
            a[1][2] = fmaf(w1, val.z, a[1][2]);
            a[1][3] = fmaf(w1, val.w, a[1][3]);
        }
#pragma unroll
        for (int q = 0; q < 2; ++q)
#pragma unroll
            for (int x = 0; x < 4; ++x) a[q][x] += __shfl_xor(a[q][x], 32);
        if (wave > 0 && lane < 32) {
#pragma unroll
            for (int q = 0; q < 2; ++q)
                s_part[wave - 1][q][l32] = make_float4(a[q][0], a[q][1], a[q][2], a[q][3]);
        }
        __syncthreads();
        if (wave == 0 && lane < 32) {
#pragma unroll
            for (int q = 0; q < 2; ++q) {
                float r0 = a[q][0], r1 = a[q][1], r2 = a[q][2], r3 = a[q][3];
#pragma unroll
                for (int w = 0; w < 3; ++w) {
                    const float4 p = s_part[w][q][l32];
                    r0 += p.x; r1 += p.y; r2 += p.z; r3 += p.w;
                }
                const float inv = s_inv[q];
                *(float4*)(out + (size_t)(b * Qn + q0 + q) * DVv + v4) =
                    make_float4(r0 * inv, r1 * inv, r2 * inv, r3 * inv);
            }
        }
    }
}

extern "C" void kernel_launch(void* const* d_in, const int* in_sizes, int n_in,
                              void* d_out, int out_size, void* d_ws, size_t ws_size,
                              hipStream_t stream) {
    (void)in_sizes; (void)n_in; (void)out_size; (void)ws_size;
    const float* queries    = (const float*)d_in[0];
    const float* keys       = (const float*)d_in[1];
    const float* values     = (const float*)d_in[2];
    const int*   valid_lens = (const int*)  d_in[3];
    const float* Wq         = (const float*)d_in[4];
    const float* Wk         = (const float*)d_in[5];
    const float* wvv        = (const float*)d_in[6];
    float* out = (float*)d_out;

    float* Wq4T = (float*)d_ws;                                  // 256*128 floats
    float* Wk4T = Wq4T + (size_t)Dd * Hh;
    float* EqT  = Wk4T + (size_t)Dd * Hh;                        // 8*128*256
    float* EkT  = EqT + (size_t)Bb * Hh * Qn;                    // 8*128*1024

    repack_w       <<<  64, 256, 0, stream>>>(Wq, Wk, (float4*)Wq4T, (float4*)Wk4T);
    proj_exp_kernel<<< 640, 256, 0, stream>>>(queries, keys, (const float4*)Wq4T,
                                              (const float4*)Wk4T, EqT, EkT);
    attn_kernel    <<<1024, 256, 0, stream>>>(EqT, EkT, wvv, values, valid_lens, out);
}

// Round 6
// 175.668 us; speedup vs baseline: 1.8852x; 1.8852x over previous
//
#include <hip/hip_runtime.h>

// Additive attention, factored:
//   scores[b,q,k] = sum_h w_h * tanh(qp+kp) ;  tanh(x) = 1 - 2/(1+e^{2x})
//   e^{2(qp+kp)} = Eq*Ek  (Eq=e^{2qp}, Ek=e^{2kp} precomputed)
// With a = sum_h w_h/(1+Eq*Ek): score = const - 2a  ->  min-form softmax:
// p = exp2((min_a - a)*2*log2e). Inner loop = fma+rcp+fma per (q,k,h).
//
// K0: repack W -> W4T[g][h] float4 (g = d/4).
// K1: proj+exp. Block = 32 rows x 128 h, thread = 4r x 4h (64 FMA / 8 LDS
//     reads per 4-d group -> VALU-bound). X tile staged once, W per chunk.
// K2: fused scores + masked softmax + P@V per (b, 2q).
//     Score phase stages Ek[16][256] tiles cooperatively in LDS (coalesced,
//     bulk-latency) -- NO per-thread register rotation (round-5 scratch bug).

#define Bb 8
#define Qn 256
#define Kk 1024
#define Dd 256
#define Hh 128
#define DVv 128

__device__ __forceinline__ float fexp2(float x) { return __builtin_amdgcn_exp2f(x); }
__device__ __forceinline__ float frcp(float x)  { return __builtin_amdgcn_rcpf(x); }

// ---------------------------------------------------------------------------
// K0: W [H][D] -> W4T [D/4][H] float4. 64 blocks x 256 threads.
// ---------------------------------------------------------------------------
__global__ __launch_bounds__(256)
void repack_w(const float* __restrict__ Wq, const float* __restrict__ Wk,
              float4* __restrict__ Wq4T, float4* __restrict__ Wk4T)
{
    const int blk = blockIdx.x;
    const float* src = (blk < 32) ? Wq : Wk;
    float4*      dst = (blk < 32) ? Wq4T : Wk4T;
    const int idx = (blk & 31) * 256 + threadIdx.x;   // 8192 float4 per matrix
    const int g = idx >> 7;
    const int h = idx & 127;
    dst[idx] = *(const float4*)(src + (size_t)h * Dd + g * 4);
}

// ---------------------------------------------------------------------------
// K1: EqT[b][h][r] = exp2(2*log2e * X[r]·W[h]).
// 320 blocks x 256 threads. Block = 32 rows x 128 h; thread = 4 rows x 4 h.
// Per 4-d group: 4 X b128 (broadcast) + 4 W b128 (16B-stride, 8/bank = min)
// + 64 FMA -> VALU-bound mix. 64 KB LDS -> 2 blocks/CU (grid is 1.25/CU).
// ---------------------------------------------------------------------------
__global__ __launch_bounds__(256, 2)
void proj_exp_kernel(const float* __restrict__ queries,
                     const float* __restrict__ keys,
                     const float4* __restrict__ Wq4T,
                     const float4* __restrict__ Wk4T,
                     float* __restrict__ EqT,
                     float* __restrict__ EkT)
{
    __shared__ float  Xs[32 * 256];      // 32 KB  [row][d]
    __shared__ float4 Ws4[16 * 128];     // 32 KB  [g-in-chunk][h]

    const int blk = blockIdx.x;          // 0..63 queries, 64..319 keys
    const float* X; const float4* W4; float* outT; int RB; int i0;
    if (blk < 64) { X = queries; W4 = Wq4T; outT = EqT; RB = Qn; i0 = blk * 32; }
    else          { X = keys;    W4 = Wk4T; outT = EkT; RB = Kk; i0 = (blk - 64) * 32; }

    const int tid = threadIdx.x;
    const int hq  = tid & 31;            // h-quad: h0 = 4*hq
    const int rg  = tid >> 5;            // row-group: r0 = 4*rg
    const int h0  = hq * 4;

    // stage full X tile: 32 rows x 256 d = 2048 float4, 8 per thread
#pragma unroll
    for (int s = 0; s < 8; ++s) {
        const int idx = tid + 256 * s;
        const int row = idx >> 6, c4 = (idx & 63) * 4;
        *(float4*)(Xs + row * 256 + c4) =
            *(const float4*)(X + (size_t)(i0 + row) * Dd + c4);
    }

    float acc[4][4];                     // [row][h]
#pragma unroll
    for (int i = 0; i < 4; ++i)
#pragma unroll
        for (int j = 0; j < 4; ++j) acc[i][j] = 0.f;

    for (int c = 0; c < 4; ++c) {        // 4 chunks of 64 d (16 g)
        const int g0 = c * 16;
        __syncthreads();                 // protects Xs (1st iter) / Ws4 reuse
#pragma unroll
        for (int s = 0; s < 8; ++s) {    // stage W chunk: 16 g x 128 h
            const int idx = tid + 256 * s;
            Ws4[idx] = W4[(size_t)(g0 + (idx >> 7)) * Hh + (idx & 127)];
        }
        __syncthreads();

#pragma unroll 4
        for (int g = 0; g < 16; ++g) {
            float4 x[4], w[4];
#pragma unroll
            for (int i = 0; i < 4; ++i)  // 2 addrs per wave -> broadcast
                x[i] = *(const float4*)(Xs + (rg * 4 + i) * 256 + (g0 + g) * 4);
#pragma unroll
            for (int j = 0; j < 4; ++j)
                w[j] = Ws4[g * 128 + h0 + j];
#pragma unroll
            for (int i = 0; i < 4; ++i)
#pragma unroll
                for (int j = 0; j < 4; ++j) {
                    acc[i][j] = fmaf(x[i].x, w[j].x, acc[i][j]);
                    acc[i][j] = fmaf(x[i].y, w[j].y, acc[i][j]);
                    acc[i][j] = fmaf(x[i].z, w[j].z, acc[i][j]);
                    acc[i][j] = fmaf(x[i].w, w[j].w, acc[i][j]);
                }
        }
    }

    const int b    = i0 / RB;            // 32 | RB, never straddles b
    const int rloc = (i0 % RB) + rg * 4;
#pragma unroll
    for (int j = 0; j < 4; ++j) {
        float4 o;
        o.x = fexp2(acc[0][j] * 2.885390082f);   // e^{2x} = 2^{2x*log2e}
        o.y = fexp2(acc[1][j] * 2.885390082f);
        o.z = fexp2(acc[2][j] * 2.885390082f);
        o.w = fexp2(acc[3][j] * 2.885390082f);
        *(float4*)(outT + (size_t)b * Hh * RB + (size_t)(h0 + j) * RB + rloc) = o;
    }
}

// ---------------------------------------------------------------------------
// K2: fused scores + masked softmax + P@V. 1024 blocks (qt<<3 | b) x 256 thr.
// Score phase: cooperative Ek[16][256] LDS tiles; thread = 1 k x 2 q.
// ---------------------------------------------------------------------------
__global__ __launch_bounds__(256, 4)
void attn_kernel(const float* __restrict__ EqT,
                 const float* __restrict__ EkT,
                 const float* __restrict__ wv,
                 const float* __restrict__ values,
                 const int* __restrict__ valid_lens,
                 float* __restrict__ out)
{
    __shared__ float4 eqpk[Hh];          // 2 KB: (eq_q0, eq_q1, wv, 0) per h
    __shared__ float  Eks[16 * 256];     // 16 KB: Ek tile [h-in-chunk][k]
    __shared__ float  s_a[2][Kk];        // 8 KB: a-scores then weights
    __shared__ float4 s_part[3][2][32];  // 3 KB: PV partials
    __shared__ float  s_inv[2];

    const int blk  = blockIdx.x;
    const int b    = blk & 7;            // fastest-varying for load balance
    const int q0   = (blk >> 3) * 2;
    const int tid  = threadIdx.x;
    const int lane = tid & 63;
    const int wave = __builtin_amdgcn_readfirstlane(tid >> 6);
    const int len  = valid_lens[b];

    // ---- stage per-h constants (one-time)
    if (tid < Hh) {
        const float2 eq = *(const float2*)(EqT + (size_t)b * Hh * Qn + (size_t)tid * Qn + q0);
        eqpk[tid] = make_float4(eq.x, eq.y, wv[tid], 0.f);
    }

    const float* ekbase = EkT + (size_t)b * Hh * Kk;

    // ---- phase 1: a[q][k] = sum_h wv[h]/(1+Eq*Ek), LDS-staged Ek tiles
    for (int k0 = 0; k0 < len; k0 += 256) {
        const int k = k0 + tid;
        float a0 = 0.f, a1 = 0.f;
        for (int hc = 0; hc < Hh; hc += 16) {
            __syncthreads();             // covers eqpk (1st) / Eks reuse
#pragma unroll
            for (int s = 0; s < 4; ++s) {   // stage 16 h x 256 k, coalesced
                const int idx = tid + 256 * s;
                const int hr = idx >> 6, c4 = (idx & 63) * 4;
                *(float4*)(Eks + hr * 256 + c4) =
                    *(const float4*)(ekbase + (size_t)(hc + hr) * Kk + k0 + c4);
            }
            __syncthreads();
            if (k < len) {
#pragma unroll
                for (int i = 0; i < 16; ++i) {
                    const float  ek = Eks[i * 256 + tid];   // stride-1, no conflict
                    const float4 c  = eqpk[hc + i];         // broadcast b128
                    a0 = fmaf(c.z, frcp(fmaf(c.x, ek, 1.0f)), a0);
                    a1 = fmaf(c.z, frcp(fmaf(c.y, ek, 1.0f)), a1);
                }
            }
        }
        if (k < len) { s_a[0][k] = a0; s_a[1][k] = a1; }
    }
    __syncthreads();

    // ---- phase 2: min-form softmax; waves 0,1 own q = wave
    if (wave < 2) {
        const int q = wave;
        float mn = 3.0e38f;
        for (int i = lane; i < len; i += 64) mn = fminf(mn, s_a[q][i]);
#pragma unroll
        for (int off = 32; off > 0; off >>= 1) mn = fminf(mn, __shfl_xor(mn, off));
        float sum = 0.f;
        for (int i = lane; i < len; i += 64) {
            const float p = fexp2((mn - s_a[q][i]) * 2.885390082f);
            s_a[q][i] = p;
            sum += p;
        }
#pragma unroll
        for (int off = 32; off > 0; off >>= 1) sum += __shfl_xor(sum, off);
        if (lane == 0) s_inv[q] = frcp(sum);
    }
    __syncthreads();

    // ---- phase 3: P@V. 8 k-slices x (32 lanes x float4 = 128 v)
    {
        const int slice = tid >> 5;
        const int l32   = tid & 31;
        const int v4    = l32 << 2;
        const float* vp = values + (size_t)b * Kk * DVv + v4;
        float a[2][4];
#pragma unroll
        for (int q = 0; q < 2; ++q) { a[q][0]=0.f; a[q][1]=0.f; a[q][2]=0.f; a[q][3]=0.f; }
        for (int k = slice; k < len; k += 8) {
            const float4 val = *(const float4*)(vp + (size_t)k * DVv);
            const float w0 = s_a[0][k];  // half-wave same k -> broadcast
            const float w1 = s_a[1][k];
            a[0][0] = fmaf(w0, val.x, a[0][0]);
            a[0][1] = fmaf(w0, val.y, a[0][1]);
            a[0][2] = fmaf(w0, val.z, a[0][2]);
            a[0][3] = fmaf(w0, val.w, a[0][3]);
            a[1][0] = fmaf(w1, val.x, a[1][0]);
            a[1][1] = fmaf(w1, val.y, a[1][1]);
            a[1][2] = fmaf(w1, val.z, a[1][2]);
            a[1][3] = fmaf(w1, val.w, a[1][3]);
        }
#pragma unroll
        for (int q = 0; q < 2; ++q)
#pragma unroll
            for (int x = 0; x < 4; ++x) a[q][x] += __shfl_xor(a[q][x], 32);
        if (wave > 0 && lane < 32) {
#pragma unroll
            for (int q = 0; q < 2; ++q)
                s_part[wave - 1][q][l32] = make_float4(a[q][0], a[q][1], a[q][2], a[q][3]);
        }
        __syncthreads();
        if (wave == 0 && lane < 32) {
#pragma unroll
            for (int q = 0; q < 2; ++q) {
                float r0 = a[q][0], r1 = a[q][1], r2 = a[q][2], r3 = a[q][3];
#pragma unroll
                for (int w = 0; w < 3; ++w) {
                    const float4 p = s_part[w][q][l32];
                    r0 += p.x; r1 += p.y; r2 += p.z; r3 += p.w;
                }
                const float inv = s_inv[q];
                *(float4*)(out + (size_t)(b * Qn + q0 + q) * DVv + v4) =
                    make_float4(r0 * inv, r1 * inv, r2 * inv, r3 * inv);
            }
        }
    }
}

extern "C" void kernel_launch(void* const* d_in, const int* in_sizes, int n_in,
                              void* d_out, int out_size, void* d_ws, size_t ws_size,
                              hipStream_t stream) {
    (void)in_sizes; (void)n_in; (void)out_size; (void)ws_size;
    const float* queries    = (const float*)d_in[0];
    const float* keys       = (const float*)d_in[1];
    const float* values     = (const float*)d_in[2];
    const int*   valid_lens = (const int*)  d_in[3];
    const float* Wq         = (const float*)d_in[4];
    const float* Wk         = (const float*)d_in[5];
    const float* wvv        = (const float*)d_in[6];
    float* out = (float*)d_out;

    float* Wq4T = (float*)d_ws;                                  // 256*128 floats
    float* Wk4T = Wq4T + (size_t)Dd * Hh;
    float* EqT  = Wk4T + (size_t)Dd * Hh;                        // 8*128*256
    float* EkT  = EqT + (size_t)Bb * Hh * Qn;                    // 8*128*1024

    repack_w       <<< 64, 256, 0, stream>>>(Wq, Wk, (float4*)Wq4T, (float4*)Wk4T);
    proj_exp_kernel<<<320, 256, 0, stream>>>(queries, keys, (const float4*)Wq4T,
                                             (const float4*)Wk4T, EqT, EkT);
    attn_kernel   <<<1024, 256, 0, stream>>>(EqT, EkT, wvv, values, valid_lens, out);
}

// Round 7
// 150.777 us; speedup vs baseline: 2.1964x; 1.1651x over previous
//
#include <hip/hip_runtime.h>

// Additive attention, factored:
//   scores[b,q,k] = sum_h w_h * tanh(qp+kp) ;  tanh(x) = 1 - 2/(1+e^{2x})
//   e^{2(qp+kp)} = Eq*Ek  (Eq=e^{2qp}, Ek=e^{2kp} precomputed)
// With a = sum_h w_h/(1+Eq*Ek): score = const - 2a  ->  min-form softmax:
// p = exp2((min_a - a)*2*log2e). Inner loop = fma+rcp+fma per (q,k,h).
//
// K0: repack W -> W4T[g][h] float4 (g = d/4).
// K1: proj+exp. Block = 32 rows x 128 h, thread = 4r x 4h. W tile stored
//     transpose-swizzled in LDS (4-way max instead of 16-way conflicts).
// K2: fused scores + masked softmax + P@V per (b, 2q).
//     Score phase: thread = 4 k (float4 ek global load, coalesced) x 2 q,
//     no LDS staging, no barriers in the loop. 4 named temps, no arrays.

#define Bb 8
#define Qn 256
#define Kk 1024
#define Dd 256
#define Hh 128
#define DVv 128

__device__ __forceinline__ float fexp2(float x) { return __builtin_amdgcn_exp2f(x); }
__device__ __forceinline__ float frcp(float x)  { return __builtin_amdgcn_rcpf(x); }

// ---------------------------------------------------------------------------
// K0: W [H][D] -> W4T [D/4][H] float4. 64 blocks x 256 threads.
// ---------------------------------------------------------------------------
__global__ __launch_bounds__(256)
void repack_w(const float* __restrict__ Wq, const float* __restrict__ Wk,
              float4* __restrict__ Wq4T, float4* __restrict__ Wk4T)
{
    const int blk = blockIdx.x;
    const float* src = (blk < 32) ? Wq : Wk;
    float4*      dst = (blk < 32) ? Wq4T : Wk4T;
    const int idx = (blk & 31) * 256 + threadIdx.x;   // 8192 float4 per matrix
    const int g = idx >> 7;
    const int h = idx & 127;
    dst[idx] = *(const float4*)(src + (size_t)h * Dd + g * 4);
}

// ---------------------------------------------------------------------------
// K1: EqT[b][h][r] = exp2(2*log2e * X[r]·W[h]).
// 320 blocks x 256 threads. Block = 32 rows x 128 h; thread = 4 rows x 4 h.
// W LDS layout swizzled: slot(h) = (h&3)*32 + (h>>2), so the 4 W reads per g
// are 4B-lane-stride (4-way = 1.58x) instead of 64B-stride (16-way).
// X reads are 2-addr-per-wave broadcasts (free).
// ---------------------------------------------------------------------------
__global__ __launch_bounds__(256, 2)
void proj_exp_kernel(const float* __restrict__ queries,
                     const float* __restrict__ keys,
                     const float4* __restrict__ Wq4T,
                     const float4* __restrict__ Wk4T,
                     float* __restrict__ EqT,
                     float* __restrict__ EkT)
{
    __shared__ float  Xs[32 * 256];      // 32 KB  [row][d]
    __shared__ float4 Ws4[16 * 128];     // 32 KB  [g-in-chunk][swizzled h]

    const int blk = blockIdx.x;          // 0..63 queries, 64..319 keys
    const float* X; const float4* W4; float* outT; int RB; int i0;
    if (blk < 64) { X = queries; W4 = Wq4T; outT = EqT; RB = Qn; i0 = blk * 32; }
    else          { X = keys;    W4 = Wk4T; outT = EkT; RB = Kk; i0 = (blk - 64) * 32; }

    const int tid = threadIdx.x;
    const int hq  = tid & 31;            // h-quad: h = 4*hq + j
    const int rg  = tid >> 5;            // row-group: r0 = 4*rg
    const int h0  = hq * 4;

    // stage full X tile: 32 rows x 256 d = 2048 float4, 8 per thread
#pragma unroll
    for (int s = 0; s < 8; ++s) {
        const int idx = tid + 256 * s;
        const int row = idx >> 6, c4 = (idx & 63) * 4;
        *(float4*)(Xs + row * 256 + c4) =
            *(const float4*)(X + (size_t)(i0 + row) * Dd + c4);
    }

    float acc[4][4];                     // [row][h]
#pragma unroll
    for (int i = 0; i < 4; ++i)
#pragma unroll
        for (int j = 0; j < 4; ++j) acc[i][j] = 0.f;

    for (int c = 0; c < 4; ++c) {        // 4 chunks of 64 d (16 g)
        const int g0 = c * 16;
        __syncthreads();                 // protects Xs (1st iter) / Ws4 reuse
#pragma unroll
        for (int s = 0; s < 8; ++s) {    // stage W chunk, slot-contiguous writes
            const int idx  = tid + 256 * s;
            const int g    = idx >> 7;
            const int slot = idx & 127;                       // j*32 + hq
            const int h    = ((slot & 31) << 2) | (slot >> 5);// inverse swizzle
            Ws4[idx] = W4[(size_t)(g0 + g) * Hh + h];
        }
        __syncthreads();

#pragma unroll 4
        for (int g = 0; g < 16; ++g) {
            float4 x[4], w[4];
#pragma unroll
            for (int i = 0; i < 4; ++i)  // 2 addrs per wave -> broadcast
                x[i] = *(const float4*)(Xs + (rg * 4 + i) * 256 + (g0 + g) * 4);
#pragma unroll
            for (int j = 0; j < 4; ++j)  // swizzled: 4B lane stride, 4-way
                w[j] = Ws4[g * 128 + j * 32 + hq];
#pragma unroll
            for (int i = 0; i < 4; ++i)
#pragma unroll
                for (int j = 0; j < 4; ++j) {
                    acc[i][j] = fmaf(x[i].x, w[j].x, acc[i][j]);
                    acc[i][j] = fmaf(x[i].y, w[j].y, acc[i][j]);
                    acc[i][j] = fmaf(x[i].z, w[j].z, acc[i][j]);
                    acc[i][j] = fmaf(x[i].w, w[j].w, acc[i][j]);
                }
        }
    }

    const int b    = i0 / RB;            // 32 | RB, never straddles b
    const int rloc = (i0 % RB) + rg * 4;
#pragma unroll
    for (int j = 0; j < 4; ++j) {
        float4 o;
        o.x = fexp2(acc[0][j] * 2.885390082f);   // e^{2x} = 2^{2x*log2e}
        o.y = fexp2(acc[1][j] * 2.885390082f);
        o.z = fexp2(acc[2][j] * 2.885390082f);
        o.w = fexp2(acc[3][j] * 2.885390082f);
        *(float4*)(outT + (size_t)b * Hh * RB + (size_t)(h0 + j) * RB + rloc) = o;
    }
}

// ---------------------------------------------------------------------------
// K2: fused scores + masked softmax + P@V. 1024 blocks (qt<<3 | b) x 256 thr.
// Score phase: thread = 4 consecutive k (float4 ek load) x 2 q; whole Kk in
// one pass (256 thr x 4 k). No LDS staging, no loop barriers.
// ---------------------------------------------------------------------------
__global__ __launch_bounds__(256, 4)
void attn_kernel(const float* __restrict__ EqT,
                 const float* __restrict__ EkT,
                 const float* __restrict__ wv,
                 const float* __restrict__ values,
                 const int* __restrict__ valid_lens,
                 float* __restrict__ out)
{
    __shared__ float4 eqpk[Hh];          // 2 KB: (eq_q0, eq_q1, wv, 0) per h
    __shared__ float  s_a[2][Kk];        // 8 KB: a-scores then weights
    __shared__ float4 s_part[3][2][32];  // 3 KB: PV partials
    __shared__ float  s_inv[2];

    const int blk  = blockIdx.x;
    const int b    = blk & 7;            // fastest-varying for load balance
    const int q0   = (blk >> 3) * 2;
    const int tid  = threadIdx.x;
    const int lane = tid & 63;
    const int wave = __builtin_amdgcn_readfirstlane(tid >> 6);
    const int len  = valid_lens[b];

    // ---- stage per-h constants (one-time)
    if (tid < Hh) {
        const float2 eq = *(const float2*)(EqT + (size_t)b * Hh * Qn + (size_t)tid * Qn + q0);
        eqpk[tid] = make_float4(eq.x, eq.y, wv[tid], 0.f);
    }
    __syncthreads();

    // ---- phase 1: a[q][k] = sum_h wv[h]/(1+Eq*Ek); thread = 4 k x 2 q
    const int k4 = tid * 4;
    if (k4 < len) {
        const float* ekp = EkT + (size_t)b * Hh * Kk + k4;
        float a00 = 0.f, a01 = 0.f, a02 = 0.f, a03 = 0.f;
        float a10 = 0.f, a11 = 0.f, a12 = 0.f, a13 = 0.f;
#pragma unroll 2
        for (int h = 0; h < Hh; h += 4) {
            const float4 ekA = *(const float4*)(ekp + (size_t)(h + 0) * Kk);
            const float4 ekB = *(const float4*)(ekp + (size_t)(h + 1) * Kk);
            const float4 ekC = *(const float4*)(ekp + (size_t)(h + 2) * Kk);
            const float4 ekD = *(const float4*)(ekp + (size_t)(h + 3) * Kk);
            const float4 cA = eqpk[h + 0];
            const float4 cB = eqpk[h + 1];
            const float4 cC = eqpk[h + 2];
            const float4 cD = eqpk[h + 3];
            a00 = fmaf(cA.z, frcp(fmaf(cA.x, ekA.x, 1.0f)), a00);
            a01 = fmaf(cA.z, frcp(fmaf(cA.x, ekA.y, 1.0f)), a01);
            a02 = fmaf(cA.z, frcp(fmaf(cA.x, ekA.z, 1.0f)), a02);
            a03 = fmaf(cA.z, frcp(fmaf(cA.x, ekA.w, 1.0f)), a03);
            a10 = fmaf(cA.z, frcp(fmaf(cA.y, ekA.x, 1.0f)), a10);
            a11 = fmaf(cA.z, frcp(fmaf(cA.y, ekA.y, 1.0f)), a11);
            a12 = fmaf(cA.z, frcp(fmaf(cA.y, ekA.z, 1.0f)), a12);
            a13 = fmaf(cA.z, frcp(fmaf(cA.y, ekA.w, 1.0f)), a13);
            a00 = fmaf(cB.z, frcp(fmaf(cB.x, ekB.x, 1.0f)), a00);
            a01 = fmaf(cB.z, frcp(fmaf(cB.x, ekB.y, 1.0f)), a01);
            a02 = fmaf(cB.z, frcp(fmaf(cB.x, ekB.z, 1.0f)), a02);
            a03 = fmaf(cB.z, frcp(fmaf(cB.x, ekB.w, 1.0f)), a03);
            a10 = fmaf(cB.z, frcp(fmaf(cB.y, ekB.x, 1.0f)), a10);
            a11 = fmaf(cB.z, frcp(fmaf(cB.y, ekB.y, 1.0f)), a11);
            a12 = fmaf(cB.z, frcp(fmaf(cB.y, ekB.z, 1.0f)), a12);
            a13 = fmaf(cB.z, frcp(fmaf(cB.y, ekB.w, 1.0f)), a13);
            a00 = fmaf(cC.z, frcp(fmaf(cC.x, ekC.x, 1.0f)), a00);
            a01 = fmaf(cC.z, frcp(fmaf(cC.x, ekC.y, 1.0f)), a01);
            a02 = fmaf(cC.z, frcp(fmaf(cC.x, ekC.z, 1.0f)), a02);
            a03 = fmaf(cC.z, frcp(fmaf(cC.x, ekC.w, 1.0f)), a03);
            a10 = fmaf(cC.z, frcp(fmaf(cC.y, ekC.x, 1.0f)), a10);
            a11 = fmaf(cC.z, frcp(fmaf(cC.y, ekC.y, 1.0f)), a11);
            a12 = fmaf(cC.z, frcp(fmaf(cC.y, ekC.z, 1.0f)), a12);
            a13 = fmaf(cC.z, frcp(fmaf(cC.y, ekC.w, 1.0f)), a13);
            a00 = fmaf(cD.z, frcp(fmaf(cD.x, ekD.x, 1.0f)), a00);
            a01 = fmaf(cD.z, frcp(fmaf(cD.x, ekD.y, 1.0f)), a01);
            a02 = fmaf(cD.z, frcp(fmaf(cD.x, ekD.z, 1.0f)), a02);
            a03 = fmaf(cD.z, frcp(fmaf(cD.x, ekD.w, 1.0f)), a03);
            a10 = fmaf(cD.z, frcp(fmaf(cD.y, ekD.x, 1.0f)), a10);
            a11 = fmaf(cD.z, frcp(fmaf(cD.y, ekD.y, 1.0f)), a11);
            a12 = fmaf(cD.z, frcp(fmaf(cD.y, ekD.z, 1.0f)), a12);
            a13 = fmaf(cD.z, frcp(fmaf(cD.y, ekD.w, 1.0f)), a13);
        }
        *(float4*)(&s_a[0][k4]) = make_float4(a00, a01, a02, a03);
        *(float4*)(&s_a[1][k4]) = make_float4(a10, a11, a12, a13);
    }
    __syncthreads();

    // ---- phase 2: min-form softmax; waves 0,1 own q = wave
    if (wave < 2) {
        const int q = wave;
        float mn = 3.0e38f;
        for (int i = lane; i < len; i += 64) mn = fminf(mn, s_a[q][i]);
#pragma unroll
        for (int off = 32; off > 0; off >>= 1) mn = fminf(mn, __shfl_xor(mn, off));
        float sum = 0.f;
        for (int i = lane; i < len; i += 64) {
            const float p = fexp2((mn - s_a[q][i]) * 2.885390082f);
            s_a[q][i] = p;
            sum += p;
        }
#pragma unroll
        for (int off = 32; off > 0; off >>= 1) sum += __shfl_xor(sum, off);
        if (lane == 0) s_inv[q] = frcp(sum);
    }
    __syncthreads();

    // ---- phase 3: P@V. 8 k-slices x (32 lanes x float4 = 128 v)
    {
        const int slice = tid >> 5;
        const int l32   = tid & 31;
        const int v4    = l32 << 2;
        const float* vp = values + (size_t)b * Kk * DVv + v4;
        float a[2][4];
#pragma unroll
        for (int q = 0; q < 2; ++q) { a[q][0]=0.f; a[q][1]=0.f; a[q][2]=0.f; a[q][3]=0.f; }
        for (int k = slice; k < len; k += 8) {
            const float4 val = *(const float4*)(vp + (size_t)k * DVv);
            const float w0 = s_a[0][k];  // half-wave same k -> broadcast
            const float w1 = s_a[1][k];
            a[0][0] = fmaf(w0, val.x, a[0][0]);
            a[0][1] = fmaf(w0, val.y, a[0][1]);
            a[0][2] = fmaf(w0, val.z, a[0][2]);
            a[0][3] = fmaf(w0, val.w, a[0][3]);
            a[1][0] = fmaf(w1, val.x, a[1][0]);
            a[1][1] = fmaf(w1, val.y, a[1][1]);
            a[1][2] = fmaf(w1, val.z, a[1][2]);
            a[1][3] = fmaf(w1, val.w, a[1][3]);
        }
#pragma unroll
        for (int q = 0; q < 2; ++q)
#pragma unroll
            for (int x = 0; x < 4; ++x) a[q][x] += __shfl_xor(a[q][x], 32);
        if (wave > 0 && lane < 32) {
#pragma unroll
            for (int q = 0; q < 2; ++q)
                s_part[wave - 1][q][l32] = make_float4(a[q][0], a[q][1], a[q][2], a[q][3]);
        }
        __syncthreads();
        if (wave == 0 && lane < 32) {
#pragma unroll
            for (int q = 0; q < 2; ++q) {
                float r0 = a[q][0], r1 = a[q][1], r2 = a[q][2], r3 = a[q][3];
#pragma unroll
                for (int w = 0; w < 3; ++w) {
                    const float4 p = s_part[w][q][l32];
                    r0 += p.x; r1 += p.y; r2 += p.z; r3 += p.w;
                }
                const float inv = s_inv[q];
                *(float4*)(out + (size_t)(b * Qn + q0 + q) * DVv + v4) =
                    make_float4(r0 * inv, r1 * inv, r2 * inv, r3 * inv);
            }
        }
    }
}

extern "C" void kernel_launch(void* const* d_in, const int* in_sizes, int n_in,
                              void* d_out, int out_size, void* d_ws, size_t ws_size,
                              hipStream_t stream) {
    (void)in_sizes; (void)n_in; (void)out_size; (void)ws_size;
    const float* queries    = (const float*)d_in[0];
    const float* keys       = (const float*)d_in[1];
    const float* values     = (const float*)d_in[2];
    const int*   valid_lens = (const int*)  d_in[3];
    const float* Wq         = (const float*)d_in[4];
    const float* Wk         = (const float*)d_in[5];
    const float* wvv        = (const float*)d_in[6];
    float* out = (float*)d_out;

    float* Wq4T = (float*)d_ws;                                  // 256*128 floats
    float* Wk4T = Wq4T + (size_t)Dd * Hh;
    float* EqT  = Wk4T + (size_t)Dd * Hh;                        // 8*128*256
    float* EkT  = EqT + (size_t)Bb * Hh * Qn;                    // 8*128*1024

    repack_w       <<< 64, 256, 0, stream>>>(Wq, Wk, (float4*)Wq4T, (float4*)Wk4T);
    proj_exp_kernel<<<320, 256, 0, stream>>>(queries, keys, (const float4*)Wq4T,
                                             (const float4*)Wk4T, EqT, EkT);
    attn_kernel   <<<1024, 256, 0, stream>>>(EqT, EkT, wvv, values, valid_lens, out);
}